// Round 1
// baseline (224.026 us; speedup 1.0000x reference)
//
#include <hip/hip_runtime.h>
#include <math.h>

#define N 6144
#define FEA 32
#define NBW 4
#define NITER 4

// ---------------- K0: pack X (f32[N][3]) -> xp (f64[N][4] = x,y,z,|x|^2) ---
__global__ __launch_bounds__(256) void k_init(const float* __restrict__ X,
                                              double* __restrict__ xp) {
    int i = blockIdx.x * 256 + threadIdx.x;
    if (i >= N) return;
    double x = (double)X[3 * i + 0];
    double y = (double)X[3 * i + 1];
    double z = (double)X[3 * i + 2];
    double* p = xp + (size_t)i * 4;
    p[0] = x; p[1] = y; p[2] = z;
    p[3] = fma(x, x, fma(y, y, z * z));   // same formula as inner loop -> diag d2 == 0 exactly
}

// ---------------- K1: per-iteration BN batch stats (sum, sumsq per feature) --
// grid = (24 chunks, NITER), block = 256. Deterministic two-level reduction.
__global__ __launch_bounds__(256) void k_mlp_stats(const float* __restrict__ Xfea,
                                                   const float* __restrict__ W1,
                                                   const float* __restrict__ b1,
                                                   float* __restrict__ partials) {
    __shared__ float w1s[FEA * FEA];
    __shared__ float hl[256][FEA + 1];
    __shared__ float r2[8][FEA][2];
    const int iter = blockIdx.y, chunk = blockIdx.x;

    const float* W1i = W1 + iter * FEA * FEA;
    for (int t = threadIdx.x; t < FEA * FEA; t += 256) w1s[t] = W1i[t];
    __syncthreads();

    const int row = chunk * 256 + threadIdx.x;
    float fea[FEA];
    const float4* fr = (const float4*)(Xfea + (size_t)row * FEA);
#pragma unroll
    for (int q = 0; q < FEA / 4; q++) {
        float4 v = fr[q];
        fea[4 * q + 0] = v.x; fea[4 * q + 1] = v.y;
        fea[4 * q + 2] = v.z; fea[4 * q + 3] = v.w;
    }
    float h[FEA];
#pragma unroll
    for (int f = 0; f < FEA; f++) h[f] = b1[iter * FEA + f];
    const float4* w1v = (const float4*)w1s;
#pragma unroll
    for (int k = 0; k < FEA; k++) {
        float a = fea[k];
#pragma unroll
        for (int f4 = 0; f4 < FEA / 4; f4++) {
            float4 wv = w1v[k * (FEA / 4) + f4];
            h[4 * f4 + 0] = fmaf(a, wv.x, h[4 * f4 + 0]);
            h[4 * f4 + 1] = fmaf(a, wv.y, h[4 * f4 + 1]);
            h[4 * f4 + 2] = fmaf(a, wv.z, h[4 * f4 + 2]);
            h[4 * f4 + 3] = fmaf(a, wv.w, h[4 * f4 + 3]);
        }
    }
#pragma unroll
    for (int f = 0; f < FEA; f++) hl[threadIdx.x][f] = h[f];
    __syncthreads();
    {
        int f = threadIdx.x & 31, g = threadIdx.x >> 5;
        float s = 0.f, q = 0.f;
#pragma unroll
        for (int r = 0; r < 32; r++) {
            float v = hl[g * 32 + r][f];
            s += v;
            q = fmaf(v, v, q);
        }
        r2[g][f][0] = s; r2[g][f][1] = q;
    }
    __syncthreads();
    if (threadIdx.x < FEA) {
        int f = threadIdx.x;
        float s = 0.f, q = 0.f;
#pragma unroll
        for (int g = 0; g < 8; g++) { s += r2[g][f][0]; q += r2[g][f][1]; }
        size_t o = ((size_t)(iter * 24 + chunk) * FEA + f) * 2;
        partials[o + 0] = s;
        partials[o + 1] = q;
    }
}

// ---------------- K2: fold BN into per-feature scale/shift --------------------
__global__ void k_bn(const float* __restrict__ partials,
                     const float* __restrict__ gamma,
                     const float* __restrict__ beta,
                     float* __restrict__ ss) {
    int iter = blockIdx.x;
    int f = threadIdx.x;   // 32 threads
    float s = 0.f, q = 0.f;
    for (int c = 0; c < 24; c++) {
        size_t o = ((size_t)(iter * 24 + c) * FEA + f) * 2;
        s += partials[o + 0];
        q += partials[o + 1];
    }
    float mu  = s / (float)N;
    float var = q / (float)N - mu * mu;          // biased var
    float rstd = 1.0f / sqrtf(var + 1e-5f);
    float sc = gamma[iter * FEA + f] * rstd;
    float sh = beta[iter * FEA + f] - mu * sc;
    ss[(iter * FEA + f) * 2 + 0] = sc;
    ss[(iter * FEA + f) * 2 + 1] = sh;
}

// ---------------- K3: recompute h, BN+ReLU, W2, softmax -> w[iter][N][4] -----
__global__ __launch_bounds__(256) void k_wts(const float* __restrict__ Xfea,
                                             const float* __restrict__ W1,
                                             const float* __restrict__ b1,
                                             const float* __restrict__ ss,
                                             const float* __restrict__ W2,
                                             const float* __restrict__ b2,
                                             float* __restrict__ wall) {
    __shared__ float w1s[FEA * FEA];
    __shared__ float w2s[FEA * NBW];
    __shared__ float scs[FEA], shs[FEA];
    const int iter = blockIdx.y, chunk = blockIdx.x;

    const float* W1i = W1 + iter * FEA * FEA;
    for (int t = threadIdx.x; t < FEA * FEA; t += 256) w1s[t] = W1i[t];
    if (threadIdx.x < FEA * NBW) w2s[threadIdx.x] = W2[iter * FEA * NBW + threadIdx.x];
    if (threadIdx.x < FEA) {
        scs[threadIdx.x] = ss[(iter * FEA + threadIdx.x) * 2 + 0];
        shs[threadIdx.x] = ss[(iter * FEA + threadIdx.x) * 2 + 1];
    }
    __syncthreads();

    const int row = chunk * 256 + threadIdx.x;
    float fea[FEA];
    const float4* fr = (const float4*)(Xfea + (size_t)row * FEA);
#pragma unroll
    for (int q = 0; q < FEA / 4; q++) {
        float4 v = fr[q];
        fea[4 * q + 0] = v.x; fea[4 * q + 1] = v.y;
        fea[4 * q + 2] = v.z; fea[4 * q + 3] = v.w;
    }
    float h[FEA];
#pragma unroll
    for (int f = 0; f < FEA; f++) h[f] = b1[iter * FEA + f];
    const float4* w1v = (const float4*)w1s;
#pragma unroll
    for (int k = 0; k < FEA; k++) {
        float a = fea[k];
#pragma unroll
        for (int f4 = 0; f4 < FEA / 4; f4++) {
            float4 wv = w1v[k * (FEA / 4) + f4];
            h[4 * f4 + 0] = fmaf(a, wv.x, h[4 * f4 + 0]);
            h[4 * f4 + 1] = fmaf(a, wv.y, h[4 * f4 + 1]);
            h[4 * f4 + 2] = fmaf(a, wv.z, h[4 * f4 + 2]);
            h[4 * f4 + 3] = fmaf(a, wv.w, h[4 * f4 + 3]);
        }
    }
    float l0 = b2[iter * NBW + 0], l1 = b2[iter * NBW + 1];
    float l2 = b2[iter * NBW + 2], l3 = b2[iter * NBW + 3];
#pragma unroll
    for (int f = 0; f < FEA; f++) {
        float hn = fmaxf(fmaf(h[f], scs[f], shs[f]), 0.0f);
        l0 = fmaf(hn, w2s[f * NBW + 0], l0);
        l1 = fmaf(hn, w2s[f * NBW + 1], l1);
        l2 = fmaf(hn, w2s[f * NBW + 2], l2);
        l3 = fmaf(hn, w2s[f * NBW + 3], l3);
    }
    float m = fmaxf(fmaxf(l0, l1), fmaxf(l2, l3));
    float e0 = expf(l0 - m), e1 = expf(l1 - m), e2 = expf(l2 - m), e3 = expf(l3 - m);
    float inv = 1.0f / (((e0 + e1) + e2) + e3);
    float4 w4;
    w4.x = e0 * inv; w4.y = e1 * inv; w4.z = e2 * inv; w4.w = e3 * inv;
    *(float4*)(wall + ((size_t)iter * N + row) * 4) = w4;
}

// ---------------- K4: one meanshift iteration (f64) --------------------------
// grid = 768 blocks, 256 threads = 4 waves x 2 rows/wave = 8 rows/block.
__global__ __launch_bounds__(256) void k_ms(const double* __restrict__ xin,
                                            double* __restrict__ xout,
                                            const float* __restrict__ wt,
                                            float* __restrict__ fout) {
    const int wv = threadIdx.x >> 6;
    const int ln = threadIdx.x & 63;
    const int r0 = blockIdx.x * 8 + wv * 2;

    double xi[2][3], sqi[2];
#pragma unroll
    for (int r = 0; r < 2; r++) {
        const double* p = xin + (size_t)(r0 + r) * 4;
        xi[r][0] = p[0]; xi[r][1] = p[1]; xi[r][2] = p[2]; sqi[r] = p[3];
    }

    double ac[2][4][3];
    int cn[2][4];
#pragma unroll
    for (int r = 0; r < 2; r++)
#pragma unroll
        for (int b = 0; b < 4; b++) {
            cn[r][b] = 0;
#pragma unroll
            for (int k = 0; k < 3; k++) ac[r][b][k] = 0.0;
        }

    const double BWSQ0 = 0.25, BWSQ1 = 1.0, BWSQ2 = 4.0, BWSQ3 = 16.0;

    for (int j0 = 0; j0 < N; j0 += 64) {
        const double* pj = xin + (size_t)(j0 + ln) * 4;
        double2 A = *(const double2*)pj;
        double2 B = *(const double2*)(pj + 2);
        double xj0 = A.x, xj1 = A.y, xj2 = B.x, sqj = B.y;
#pragma unroll
        for (int r = 0; r < 2; r++) {
            double t  = fma(xi[r][0], xj0, fma(xi[r][1], xj1, xi[r][2] * xj2));
            double d2 = fma(-2.0, t, sqi[r] + sqj);
            {
                bool m = d2 <= BWSQ0; double md = m ? 1.0 : 0.0; cn[r][0] += m;
                ac[r][0][0] = fma(md, xj0, ac[r][0][0]);
                ac[r][0][1] = fma(md, xj1, ac[r][0][1]);
                ac[r][0][2] = fma(md, xj2, ac[r][0][2]);
            }
            {
                bool m = d2 <= BWSQ1; double md = m ? 1.0 : 0.0; cn[r][1] += m;
                ac[r][1][0] = fma(md, xj0, ac[r][1][0]);
                ac[r][1][1] = fma(md, xj1, ac[r][1][1]);
                ac[r][1][2] = fma(md, xj2, ac[r][1][2]);
            }
            {
                bool m = d2 <= BWSQ2; double md = m ? 1.0 : 0.0; cn[r][2] += m;
                ac[r][2][0] = fma(md, xj0, ac[r][2][0]);
                ac[r][2][1] = fma(md, xj1, ac[r][2][1]);
                ac[r][2][2] = fma(md, xj2, ac[r][2][2]);
            }
            {
                bool m = d2 <= BWSQ3; double md = m ? 1.0 : 0.0; cn[r][3] += m;
                ac[r][3][0] = fma(md, xj0, ac[r][3][0]);
                ac[r][3][1] = fma(md, xj1, ac[r][3][1]);
                ac[r][3][2] = fma(md, xj2, ac[r][3][2]);
            }
        }
    }

    // deterministic fixed-tree wave reduction (64 lanes)
#pragma unroll
    for (int r = 0; r < 2; r++) {
#pragma unroll
        for (int b = 0; b < 4; b++) {
#pragma unroll
            for (int k = 0; k < 3; k++) {
                double v = ac[r][b][k];
#pragma unroll
                for (int off = 32; off; off >>= 1) v += __shfl_xor(v, off, 64);
                ac[r][b][k] = v;
            }
            int c = cn[r][b];
#pragma unroll
            for (int off = 32; off; off >>= 1) c += __shfl_xor(c, off, 64);
            cn[r][b] = c;
        }
    }

    if (ln == 0) {
#pragma unroll
        for (int r = 0; r < 2; r++) {
            const int row = r0 + r;
            const float* wr = wt + (size_t)row * 4;
            double w0 = (double)wr[0], w1 = (double)wr[1];
            double w2 = (double)wr[2], w3 = (double)wr[3];
            double wsum = ((w0 + w1) + w2) + w3;
            double c0 = (double)cn[r][0], c1 = (double)cn[r][1];
            double c2 = (double)cn[r][2], c3 = (double)cn[r][3];
            double o[3];
#pragma unroll
            for (int k = 0; k < 3; k++) {
                double s = w0 * (ac[r][0][k] / c0);
                s = fma(w1, ac[r][1][k] / c1, s);
                s = fma(w2, ac[r][2][k] / c2, s);
                s = fma(w3, ac[r][3][k] / c3, s);
                o[k] = s / wsum;
            }
            double* po = xout + (size_t)row * 4;
            po[0] = o[0]; po[1] = o[1]; po[2] = o[2];
            po[3] = fma(o[0], o[0], fma(o[1], o[1], o[2] * o[2]));
            float* pf = fout + (size_t)row * 3;
            pf[0] = (float)o[0]; pf[1] = (float)o[1]; pf[2] = (float)o[2];
        }
    }
}

extern "C" void kernel_launch(void* const* d_in, const int* in_sizes, int n_in,
                              void* d_out, int out_size, void* d_ws, size_t ws_size,
                              hipStream_t stream) {
    const float* X     = (const float*)d_in[0];
    const float* Xfea  = (const float*)d_in[1];
    const float* W1    = (const float*)d_in[2];
    const float* b1    = (const float*)d_in[3];
    const float* gamma = (const float*)d_in[4];
    const float* beta  = (const float*)d_in[5];
    const float* W2    = (const float*)d_in[6];
    const float* b2    = (const float*)d_in[7];
    float* out = (float*)d_out;

    // ws layout
    char* ws = (char*)d_ws;
    double* xp    = (double*)ws;                       // [2][N][4] f64  = 393216 B
    float*  wall  = (float*)(ws + 393216);             // [4][N][4] f32  = 393216 B
    float*  parts = (float*)(ws + 786432);             // [4][24][32][2] = 24576 B
    float*  ssbuf = (float*)(ws + 811008);             // [4][32][2]     = 1024 B

    k_init<<<24, 256, 0, stream>>>(X, xp);
    k_mlp_stats<<<dim3(24, NITER), 256, 0, stream>>>(Xfea, W1, b1, parts);
    k_bn<<<NITER, 32, 0, stream>>>(parts, gamma, beta, ssbuf);
    k_wts<<<dim3(24, NITER), 256, 0, stream>>>(Xfea, W1, b1, ssbuf, W2, b2, wall);

    for (int it = 0; it < NITER; it++) {
        const double* xin  = xp + (size_t)(it & 1) * N * 4;
        double*       xout = xp + (size_t)((it + 1) & 1) * N * 4;
        k_ms<<<768, 256, 0, stream>>>(xin, xout, wall + (size_t)it * N * 4, out);
    }
}